// Round 8
// baseline (1189.187 us; speedup 1.0000x reference)
//
#include <hip/hip_runtime.h>

#define NV 10000
#define NB 4
#define NTT 12
#define NSEQ 48
#define NH 3
#define NE 512
#define NS 32
#define ND 64

// ---- fixed workspace layout (element indices; float and int regions share the base) ----
#define S_U   0
#define S_C1  64
#define S_V1  128
#define S_V2  192
#define S_SC  256
#define S_GU  272
#define S_GC  528
#define S_G0  784
#define F_INV 1040
#define F_M   (F_INV + NH*NV)            // 31040
#define F_PQ  (F_M + NH*NV)              // 61040  (4 x NV*NSEQ: p0,q0,p1,q1)
#define F_HT  (F_PQ + 4*NV*NSEQ)         // 1981040 (kept for layout stability)
#define I_CNT (F_HT + 2*NB*NV)           // 2061040
#define I_CUR (I_CNT + NH*NV)
#define I_OFF (I_CUR + NH*NV)
#define I_SLOT (I_OFF + NH*NV)
#define I_SEM (I_SLOT + NH*NE*NS)        // 64 ints of semaphores
#define F_DYN (I_SEM + 64)
#define XT_SZ  (NV*NSEQ)                 // 480000
#define AGG_SZ (NH*NE*NSEQ)              // 73728
#define Y_SZ   (NH*NV*NSEQ)              // 1440000

#define T1 (NH*NE*12)                    // 18432 edge float4-groups
#define T2 (NH*NV*12)                    // 360000 vertex float4-groups
#define T3 (NV*12)                       // 120000 attn float4-groups
#define NCHUNK 79                        // ceil(NV/128)
#define SGRID 512                        // persistent-kernel grid (2 blocks/CU guaranteed)

typedef __attribute__((ext_vector_type(8))) __bf16 bf16x8;
typedef __attribute__((ext_vector_type(4))) float f32x4;

__device__ __forceinline__ float sigf(float x) {
  return __builtin_amdgcn_rcpf(1.0f + __expf(-x));
}
__device__ __forceinline__ float tanh_fast(float x) {
  return 1.0f - 2.0f * __builtin_amdgcn_rcpf(1.0f + __expf(2.0f * x));
}
__device__ __forceinline__ unsigned short f2bf(float x) {
  unsigned int u = __float_as_uint(x);
  u = (u + 0x7fffu + ((u >> 16) & 1u)) >> 16;
  return (unsigned short)u;
}
__device__ __forceinline__ float bf2f(unsigned short h) {
  return __uint_as_float(((unsigned int)h) << 16);
}
__device__ __forceinline__ bf16x8 ldsA(const unsigned short* p) {
  union { uint4 u; bf16x8 v; } x;
  x.u = *(const uint4*)p;
  return x.v;
}

// device-scope barrier for co-resident grid (grid <= guaranteed capacity)
__device__ __forceinline__ void gbar(int* sem, int n) {
  __syncthreads();
  if (threadIdx.x == 0) {
    __threadfence();
    atomicAdd(sem, 1);
    while (__hip_atomic_load(sem, __ATOMIC_ACQUIRE, __HIP_MEMORY_SCOPE_AGENT) < n)
      __builtin_amdgcn_s_sleep(2);
  }
  __syncthreads();
}

// ---------------- K1: zero counters/sems + out init + weight precompute ----------------
__global__ void k_init(const float* __restrict__ w1, const float* __restrict__ b1,
                       const float* __restrict__ w2, const float* __restrict__ b2,
                       const float* __restrict__ attn_w, const float* __restrict__ attn_a,
                       const float* __restrict__ w_ih, const float* __restrict__ b_ih,
                       const float* __restrict__ b_hh, const float* __restrict__ b_out,
                       float* __restrict__ ws, float* __restrict__ out) {
  __shared__ float u_s[64], c1_s[64];
  int* iws = (int*)ws;
  int* cnt = iws + I_CNT;  // cnt then cur (contiguous 2*NH*NV)
  const int tid = threadIdx.x;
  const int g = blockIdx.x * 256 + tid;
  const int gsz = gridDim.x * 256;
  for (int i = g; i < 2 * NH * NV; i += gsz) cnt[i] = 0;
  if (g < 64) iws[I_SEM + g] = 0;
  const float bo = b_out[0];
  for (int i = g; i < NB * NV; i += gsz) out[i] = bo;
  if (blockIdx.x == 0) {
    if (tid < 64) {
      float v1 = 0.f, v2 = 0.f, u = 0.f, c1 = 0.f;
      for (int d = 0; d < 64; ++d) {
        const float aw = attn_w[tid * 64 + d];
        v1 += aw * attn_a[d];
        v2 += aw * attn_a[64 + d];
        const float w2v = w2[d * 64 + tid];
        u  += w1[d] * w2v;
        c1 += b1[d] * w2v;
      }
      ws[S_U + tid] = u;  ws[S_C1 + tid] = c1;
      ws[S_V1 + tid] = v1; ws[S_V2 + tid] = v2;
      u_s[tid] = u; c1_s[tid] = c1;
    }
    __syncthreads();
    if (tid == 0) {
      float al = 0.f, be = 0.f, ga = 0.f, de = 0.f, ep = 0.f;
      for (int d = 0; d < 64; ++d) {
        const float v1 = ws[S_V1 + d], v2 = ws[S_V2 + d];
        al += u_s[d] * v1;  be += c1_s[d] * v1;
        ga += u_s[d] * v2;  de += c1_s[d] * v2;
        ep += b2[d] * (v1 + v2);
      }
      ws[S_SC + 0] = al; ws[S_SC + 1] = be; ws[S_SC + 2] = ga;
      ws[S_SC + 3] = de; ws[S_SC + 4] = ep;
    }
    {
      float gu = 0.f, gc = 0.f, g0 = 0.f;
      for (int d = 0; d < 64; ++d) {
        const float w = w_ih[tid * 64 + d];
        gu += w * u_s[d]; gc += w * c1_s[d]; g0 += w * b2[d];
      }
      ws[S_GU + tid] = gu; ws[S_GC + tid] = gc;
      ws[S_G0 + tid] = g0 + b_ih[tid] + b_hh[tid];
    }
  }
}

// ---------------- K2: persistent graph pipeline (5 internal device barriers) ----------
// P1: degree count (atomics) + transpose seq->xT
// P2: offset scan (blocks 0..2) || edge-agg1 (blocks 3..)
// P3: CSR fill
// P4: vertex-agg1 (normalized y)
// P5: edge-agg2
// P6: fused vertex-agg2 + attention -> p,q
__launch_bounds__(256, 2)
__global__ void k_super(const int* __restrict__ edges, const float* __restrict__ s0,
                        const float* __restrict__ s1, float* __restrict__ ws,
                        int nbr, int br0, int do_setup, int semBase) {
  __shared__ union {
    float tile[128][49];
    int sd[256];
  } sh;
  int* iws = (int*)ws;
  int* cnt = iws + I_CNT;
  int* cur = iws + I_CUR;
  int* off = iws + I_OFF;
  int* sed = iws + I_SLOT;
  int* sem = iws + I_SEM + semBase;
  const int tid = threadIdx.x;
  const int g = blockIdx.x * 256 + tid;
  const int gsz = SGRID * 256;

  // ---- P1: count + transpose ----
  if (do_setup && g < NH * NE * NS)
    atomicAdd(&cnt[(g >> 14) * NV + edges[g]], 1);
  for (int task = blockIdx.x; task < nbr * NCHUNK; task += SGRID) {
    const int bi = task / NCHUNK;
    const int chunk = task - bi * NCHUNK;
    const float* seq = (br0 + bi) ? s1 : s0;
    float* o = ws + F_DYN + (size_t)bi * XT_SZ;
    const int v0 = chunk * 128;
    __syncthreads();
    for (int i = tid; i < 128 * NSEQ; i += 256) {
      const int n = i / 128, vl = i % 128;
      const int v = v0 + vl;
      sh.tile[vl][n] = (v < NV) ? seq[n * NV + v] : 0.0f;
    }
    __syncthreads();
    for (int i = tid; i < 128 * NSEQ; i += 256) {
      const int vl = i / NSEQ, n = i % NSEQ;
      const int v = v0 + vl;
      if (v < NV) o[v * NSEQ + n] = sh.tile[vl][n];
    }
  }
  gbar(&sem[0], SGRID);

  // ---- P2: scan (blocks 0..2) || edge-agg1 (blocks 3..) ----
  if (blockIdx.x < NH) {
    if (do_setup) {
      const int h = blockIdx.x;
      const int base = h * NV;
      int run = 0;
      for (int i = 0; i < 40; ++i) {
        const int v = tid * 40 + i;
        if (v < NV) run += cnt[base + v];
      }
      sh.sd[tid] = run;
      __syncthreads();
      int acc = run;
      for (int o2 = 1; o2 < 256; o2 <<= 1) {
        const int t = (tid >= o2) ? sh.sd[tid - o2] : 0;
        __syncthreads();
        acc += t; sh.sd[tid] = acc;
        __syncthreads();
      }
      int excl = acc - run;
      for (int i = 0; i < 40; ++i) {
        const int v = tid * 40 + i;
        if (v < NV) {
          const int c = cnt[base + v];
          off[base + v] = excl; excl += c;
          ws[F_INV + base + v] = 1.0f / (float)((c > 0) ? c : 1);
          ws[F_M + base + v] = (c > 0) ? 1.0f : 0.0f;
        }
      }
    }
  } else {
    const int i = (blockIdx.x - NH) * 256 + tid;
    if (i < nbr * T1) {
      const int bi = i / T1;
      const int gg = i - bi * T1;
      const float* x = ws + F_DYN + (size_t)bi * XT_SZ;
      float* a = ws + F_DYN + (size_t)nbr * XT_SZ + (size_t)bi * AGG_SZ;
      const int n0 = (gg % 12) * 4;
      const int e = (gg / 12) % NE;
      const int h = gg / (12 * NE);
      const int* ep = edges + (h * NE + e) * NS;
      float4 acc = make_float4(0.f, 0.f, 0.f, 0.f);
      for (int s = 0; s < NS; ++s) {
        const float4 t = *(const float4*)&x[ep[s] * NSEQ + n0];
        acc.x += t.x; acc.y += t.y; acc.z += t.z; acc.w += t.w;
      }
      acc.x *= (1.0f / NS); acc.y *= (1.0f / NS); acc.z *= (1.0f / NS); acc.w *= (1.0f / NS);
      *(float4*)&a[(h * NE + e) * NSEQ + n0] = acc;
    }
  }
  gbar(&sem[1], SGRID);

  // ---- P3: CSR fill ----
  if (do_setup && g < NH * NE * NS) {
    const int h = g >> 14;
    const int e = (g >> 5) & (NE - 1);
    const int v = edges[g];
    const int pos = atomicAdd(&cur[h * NV + v], 1);
    sed[h * NE * NS + off[h * NV + v] + pos] = e;
  }
  gbar(&sem[2], SGRID);

  // ---- P4: vertex-agg1 ----
  for (int i = g; i < nbr * T2; i += gsz) {
    const int bi = i / T2;
    const int gg = i - bi * T2;
    const float* a = ws + F_DYN + (size_t)nbr * XT_SZ + (size_t)bi * AGG_SZ;
    float* y = ws + F_DYN + (size_t)nbr * (XT_SZ + AGG_SZ) + (size_t)bi * Y_SZ;
    const int n0 = (gg % 12) * 4;
    const int v = (gg / 12) % NV;
    const int h = gg / (12 * NV);
    const int beg = off[h * NV + v];
    const int cv = cnt[h * NV + v];
    const int* se = sed + h * NE * NS;
    float4 acc = make_float4(0.f, 0.f, 0.f, 0.f);
    for (int k = 0; k < cv; ++k) {
      const int e = se[beg + k];
      const float4 t = *(const float4*)&a[(h * NE + e) * NSEQ + n0];
      acc.x += t.x; acc.y += t.y; acc.z += t.z; acc.w += t.w;
    }
    const float iv = ws[F_INV + h * NV + v];
    acc.x *= iv; acc.y *= iv; acc.z *= iv; acc.w *= iv;
    *(float4*)&y[(h * NV + v) * NSEQ + n0] = acc;
  }
  gbar(&sem[3], SGRID);

  // ---- P5: edge-agg2 ----
  if (g < nbr * T1) {
    const int bi = g / T1;
    const int gg = g - bi * T1;
    const float* y = ws + F_DYN + (size_t)nbr * (XT_SZ + AGG_SZ) + (size_t)bi * Y_SZ;
    float* a = ws + F_DYN + (size_t)nbr * XT_SZ + (size_t)bi * AGG_SZ;
    const int n0 = (gg % 12) * 4;
    const int e = (gg / 12) % NE;
    const int h = gg / (12 * NE);
    const int* ep = edges + (h * NE + e) * NS;
    float4 acc = make_float4(0.f, 0.f, 0.f, 0.f);
    for (int s = 0; s < NS; ++s) {
      const float4 t = *(const float4*)&y[(h * NV + ep[s]) * NSEQ + n0];
      acc.x += t.x; acc.y += t.y; acc.z += t.z; acc.w += t.w;
    }
    acc.x *= (1.0f / NS); acc.y *= (1.0f / NS); acc.z *= (1.0f / NS); acc.w *= (1.0f / NS);
    *(float4*)&a[(h * NE + e) * NSEQ + n0] = acc;
  }
  gbar(&sem[4], SGRID);

  // ---- P6: fused vertex-agg2 + attention ----
  {
    const float al = ws[S_SC + 0], be = ws[S_SC + 1], ga = ws[S_SC + 2],
                de = ws[S_SC + 3], ep5 = ws[S_SC + 4];
    for (int i = g; i < nbr * T3; i += gsz) {
      const int bi = i / T3;
      const int gg = i - bi * T3;
      const float* a = ws + F_DYN + (size_t)nbr * XT_SZ + (size_t)bi * AGG_SZ;
      float* pbuf = ws + F_PQ + (size_t)(br0 + bi) * 2 * NV * NSEQ;
      float* qbuf = pbuf + NV * NSEQ;
      const int n0 = (gg % 12) * 4;
      const int v = gg / 12;
      union { float4 v4; float f[4]; } zh[3], pv, qv;
      float mh[3];
      #pragma unroll
      for (int h = 0; h < NH; ++h) {
        const int beg = off[h * NV + v];
        const int cv = cnt[h * NV + v];
        const int* se = sed + h * NE * NS;
        float4 acc = make_float4(0.f, 0.f, 0.f, 0.f);
        for (int k = 0; k < cv; ++k) {
          const int e = se[beg + k];
          const float4 t = *(const float4*)&a[(h * NE + e) * NSEQ + n0];
          acc.x += t.x; acc.y += t.y; acc.z += t.z; acc.w += t.w;
        }
        const float iv = ws[F_INV + h * NV + v];
        acc.x *= iv; acc.y *= iv; acc.z *= iv; acc.w *= iv;
        zh[h].v4 = acc;
        mh[h] = ws[F_M + h * NV + v];
      }
      const float mb = (mh[0] + mh[1] + mh[2]) * (1.f / 3.f);
      #pragma unroll
      for (int j = 0; j < 4; ++j) {
        const float z0 = zh[0].f[j], z1 = zh[1].f[j], z2 = zh[2].f[j];
        const float zb = (z0 + z1 + z2) * (1.f / 3.f);
        const float zt[3] = {z0, z1, z2};
        float sc[3];
        #pragma unroll
        for (int h = 0; h < NH; ++h) {
          const float s = al * zt[h] + be * mh[h] + ga * zb + de * mb + ep5;
          sc[h] = (s > 0.f) ? s : 0.2f * s;
        }
        const float mx = fmaxf(sc[0], fmaxf(sc[1], sc[2]));
        const float e0 = __expf(sc[0] - mx), e1 = __expf(sc[1] - mx), e2 = __expf(sc[2] - mx);
        const float inv = 1.0f / (e0 + e1 + e2);
        pv.f[j] = (e0 * z0 + e1 * z1 + e2 * z2) * inv;
        qv.f[j] = (e0 * mh[0] + e1 * mh[1] + e2 * mh[2]) * inv;
      }
      *(float4*)&pbuf[v * NSEQ + n0] = pv.v4;
      *(float4*)&qbuf[v * NSEQ + n0] = qv.v4;
    }
  }
}

// ---------------- MFMA LSTM ----------------
// Block: 64 vertices (seqs), batch b = blockIdx.y, branch = blockIdx.z.
// gates = xg + h @ w_hh^T via mfma_f32_16x16x32_bf16; h carried as split bf16 hi+lo.
// w_hh staged once into LDS; region reused as h double-buffer. p/q staged bf16-packed.
// LDS = 34816 + 3072 = 37888 B. NOTE: needs ~116 VGPRs — do NOT bound below 128
// (launch_bounds(256,4) forced 64 VGPR and spilled 768 MB to scratch; round 7).
#define RS  136  // h row stride (ushorts): 64 hi + 64 lo + 8 pad, 272 B (16B-aligned)
__launch_bounds__(256, 2)
__global__ void k_lstm2(const float* __restrict__ w_hh, const float* __restrict__ ws,
                        const float* __restrict__ pbase, const float* __restrict__ w_out,
                        float* __restrict__ out) {
  __shared__ __align__(16) unsigned short smem[2 * 64 * RS];  // 34816 B
  __shared__ unsigned int pq_sh[NTT][64];                     // 3072 B: (bf16 p)|(bf16 q<<16)
  const int tid = threadIdx.x;
  const int w = tid >> 6, lane = tid & 63, q = lane >> 4, l15 = lane & 15;
  const int b = blockIdx.y, br = blockIdx.z;
  const int v0 = blockIdx.x * 64;
  const int d = w * 16 + l15;  // this lane's gate-dim within [0,64)

  // coalesced stage: w_hh fp32 [256][64] -> smem bf16 [j][64] (no pad; one-time)
  for (int i = tid; i < 4096; i += 256) {
    const float4 w4 = ((const float4*)w_hh)[i];
    const int j = i >> 4, k = (i & 15) * 4;
    uint2 pk;
    pk.x = (unsigned int)f2bf(w4.x) | ((unsigned int)f2bf(w4.y) << 16);
    pk.y = (unsigned int)f2bf(w4.z) | ((unsigned int)f2bf(w4.w) << 16);
    *(uint2*)&smem[j * 64 + k] = pk;
  }
  // stage p,q for all 12 steps, packed bf16
  const float* pp = pbase + (size_t)br * 2 * NV * NSEQ;
  const float* qq = pp + NV * NSEQ;
  for (int i = tid; i < 192; i += 256) {
    const int s = i / 3, f4 = i % 3;
    const int v = v0 + s;
    float4 vp = make_float4(0.f, 0.f, 0.f, 0.f);
    float4 vq = vp;
    if (v < NV) {
      const int idx = v * NSEQ + b * NTT + f4 * 4;
      vp = *(const float4*)&pp[idx];
      vq = *(const float4*)&qq[idx];
    }
    pq_sh[f4 * 4 + 0][s] = (unsigned int)f2bf(vp.x) | ((unsigned int)f2bf(vq.x) << 16);
    pq_sh[f4 * 4 + 1][s] = (unsigned int)f2bf(vp.y) | ((unsigned int)f2bf(vq.y) << 16);
    pq_sh[f4 * 4 + 2][s] = (unsigned int)f2bf(vp.z) | ((unsigned int)f2bf(vq.z) << 16);
    pq_sh[f4 * 4 + 3][s] = (unsigned int)f2bf(vp.w) | ((unsigned int)f2bf(vq.w) << 16);
  }
  __syncthreads();

  // B fragments from LDS: B[k][n=gate g*64+d], k = kh*32 + q*8 + j (one-time, conflicts ok)
  bf16x8 Bf[4][2];
  #pragma unroll
  for (int g = 0; g < 4; ++g)
    #pragma unroll
    for (int kh = 0; kh < 2; ++kh)
      Bf[g][kh] = ldsA(&smem[(g * 64 + d) * 64 + kh * 32 + q * 8]);

  float GUr[4], GCr[4], G0r[4];
  #pragma unroll
  for (int g = 0; g < 4; ++g) {
    GUr[g] = ws[S_GU + g * 64 + d];
    GCr[g] = ws[S_GC + g * 64 + d];
    G0r[g] = ws[S_G0 + g * 64 + d];
  }
  const float WO = w_out[br * 64 + d];
  __syncthreads();  // all waves done reading w-stage; reuse smem as h dbuf

  f32x4 acc[4][4];  // [mi seq-tile][g gate-type]
  f32x4 cst[4];
  float pr[4][4];   // last-step output partials
  #pragma unroll
  for (int mi = 0; mi < 4; ++mi) cst[mi] = (f32x4){0.f, 0.f, 0.f, 0.f};

  #pragma unroll 1
  for (int t = 0; t < NTT; ++t) {
    // input contribution: xg = p*GU + q*GC + G0 (D layout: row s=mi*16+q*4+r, col d)
    #pragma unroll
    for (int mi = 0; mi < 4; ++mi)
      #pragma unroll
      for (int r = 0; r < 4; ++r) {
        const int s = mi * 16 + q * 4 + r;
        const unsigned int u = pq_sh[t][s];
        const float pv = __uint_as_float(u << 16);
        const float qv = __uint_as_float(u & 0xffff0000u);
        #pragma unroll
        for (int g = 0; g < 4; ++g)
          acc[mi][g][r] = fmaf(pv, GUr[g], fmaf(qv, GCr[g], G0r[g]));
      }
    if (t > 0) {
      const unsigned short* hr = smem + ((t - 1) & 1) * (64 * RS);
      #pragma unroll
      for (int kh = 0; kh < 2; ++kh)
        #pragma unroll
        for (int mi = 0; mi < 4; ++mi) {
          const int row = mi * 16 + l15;  // A layout: m = lane&15
          const int col = kh * 32 + q * 8;
          const bf16x8 Ahi = ldsA(&hr[row * RS + col]);
          const bf16x8 Alo = ldsA(&hr[row * RS + 64 + col]);
          #pragma unroll
          for (int g = 0; g < 4; ++g) {
            acc[mi][g] = __builtin_amdgcn_mfma_f32_16x16x32_bf16(Ahi, Bf[g][kh], acc[mi][g], 0, 0, 0);
            acc[mi][g] = __builtin_amdgcn_mfma_f32_16x16x32_bf16(Alo, Bf[g][kh], acc[mi][g], 0, 0, 0);
          }
        }
    }
    unsigned short* hw = smem + (t & 1) * (64 * RS);
    const bool last = (t == NTT - 1);
    #pragma unroll
    for (int mi = 0; mi < 4; ++mi)
      #pragma unroll
      for (int r = 0; r < 4; ++r) {
        const float ig = sigf(acc[mi][0][r]);
        const float fg = sigf(acc[mi][1][r]);
        const float gg = tanh_fast(acc[mi][2][r]);
        const float og = sigf(acc[mi][3][r]);
        const float cn = fmaf(fg, cst[mi][r], ig * gg);
        cst[mi][r] = cn;
        const float h = og * tanh_fast(cn);
        const int s = mi * 16 + q * 4 + r;
        if (!last) {
          const unsigned short hi = f2bf(h);
          const unsigned short lo = f2bf(h - bf2f(hi));
          hw[s * RS + d] = hi;
          hw[s * RS + 64 + d] = lo;
        } else {
          pr[mi][r] = h * WO;
        }
      }
    __syncthreads();
  }
  // cross-lane (16 dims of this wave) then cross-wave reduce via the dead h buffer
  float* fbuf = (float*)smem;
  #pragma unroll
  for (int mi = 0; mi < 4; ++mi)
    #pragma unroll
    for (int r = 0; r < 4; ++r) {
      float v = pr[mi][r];
      v += __shfl_xor(v, 1);
      v += __shfl_xor(v, 2);
      v += __shfl_xor(v, 4);
      v += __shfl_xor(v, 8);
      if (l15 == 0) fbuf[w * 64 + mi * 16 + q * 4 + r] = v;
    }
  __syncthreads();
  if (tid < 64) {
    const int v = v0 + tid;
    if (v < NV)
      atomicAdd(&out[b * NV + v],
                fbuf[tid] + fbuf[64 + tid] + fbuf[128 + tid] + fbuf[192 + tid]);
  }
}

extern "C" void kernel_launch(void* const* d_in, const int* in_sizes, int n_in,
                              void* d_out, int out_size, void* d_ws, size_t ws_size,
                              hipStream_t stream) {
  const float* tend   = (const float*)d_in[0];
  const float* peri   = (const float*)d_in[1];
  const int*   edges  = (const int*)d_in[2];
  const float* w1     = (const float*)d_in[3];
  const float* b1     = (const float*)d_in[4];
  const float* w2     = (const float*)d_in[5];
  const float* b2     = (const float*)d_in[6];
  const float* attn_w = (const float*)d_in[7];
  const float* attn_a = (const float*)d_in[8];
  const float* w_ih   = (const float*)d_in[9];
  const float* w_hh   = (const float*)d_in[10];
  const float* b_ih   = (const float*)d_in[11];
  const float* b_hh   = (const float*)d_in[12];
  const float* w_out  = (const float*)d_in[13];
  const float* b_out  = (const float*)d_in[14];
  float* out = (float*)d_out;
  float* ws  = (float*)d_ws;

  const size_t need2 = ((size_t)F_DYN + 2 * (XT_SZ + AGG_SZ + Y_SZ)) * 4;
  const bool batched = ws_size >= need2;

  k_init<<<128, 256, 0, stream>>>(w1, b1, w2, b2, attn_w, attn_a, w_ih, b_ih, b_hh,
                                  b_out, ws, out);
  if (batched) {
    k_super<<<SGRID, 256, 0, stream>>>(edges, tend, peri, ws, 2, 0, 1, 0);
  } else {
    k_super<<<SGRID, 256, 0, stream>>>(edges, tend, peri, ws, 1, 0, 1, 0);
    k_super<<<SGRID, 256, 0, stream>>>(edges, tend, peri, ws, 1, 1, 0, 8);
  }
  dim3 lgrid((NV + 63) / 64, NB, 2);
  k_lstm2<<<lgrid, 256, 0, stream>>>(w_hh, ws, ws + F_PQ, w_out, out);
}

// Round 9
// 376.954 us; speedup vs baseline: 3.1547x; 3.1547x over previous
//
#include <hip/hip_runtime.h>

#define NV 10000
#define NB 4
#define NTT 12
#define NSEQ 48
#define NH 3
#define NE 512
#define NS 32
#define ND 64

// ---- fixed workspace layout (element indices; float and int regions share the base) ----
#define S_U   0
#define S_C1  64
#define S_V1  128
#define S_V2  192
#define S_SC  256
#define S_GU  272
#define S_GC  528
#define S_G0  784
#define F_INV 1040
#define F_M   (F_INV + NH*NV)            // 31040
#define F_PQ  (F_M + NH*NV)              // 61040  (4 x NV*NSEQ: p0,q0,p1,q1)
#define F_HT  (F_PQ + 4*NV*NSEQ)         // 1981040 (kept for layout stability)
#define I_CNT (F_HT + 2*NB*NV)           // 2061040
#define I_CUR (I_CNT + NH*NV)
#define I_OFF (I_CUR + NH*NV)
#define I_SLOT (I_OFF + NH*NV)
#define F_DYN (I_SLOT + NH*NE*NS)        // 2200192
#define XT_SZ  (NV*NSEQ)                 // 480000
#define AGG_SZ (NH*NE*NSEQ)              // 73728
#define Y_SZ   (NH*NV*NSEQ)              // 1440000

#define T1 (NH*NE*12)                    // 18432 edge float4-groups
#define T2 (NH*NV*12)                    // 360000 vertex float4-groups
#define T3 (NV*12)                       // 120000 attn float4-groups
#define NCHUNK 79                        // ceil(NV/128)

typedef __attribute__((ext_vector_type(8))) __bf16 bf16x8;
typedef __attribute__((ext_vector_type(4))) float f32x4;

__device__ __forceinline__ float sigf(float x) {
  return __builtin_amdgcn_rcpf(1.0f + __expf(-x));
}
__device__ __forceinline__ float tanh_fast(float x) {
  return 1.0f - 2.0f * __builtin_amdgcn_rcpf(1.0f + __expf(2.0f * x));
}
__device__ __forceinline__ unsigned short f2bf(float x) {
  unsigned int u = __float_as_uint(x);
  u = (u + 0x7fffu + ((u >> 16) & 1u)) >> 16;
  return (unsigned short)u;
}
__device__ __forceinline__ float bf2f(unsigned short h) {
  return __uint_as_float(((unsigned int)h) << 16);
}
__device__ __forceinline__ bf16x8 ldsA(const unsigned short* p) {
  union { uint4 u; bf16x8 v; } x;
  x.u = *(const uint4*)p;
  return x.v;
}

// ---------------- K1: out init + weight precompute + degree count ----------------
// cnt/cur are zeroed by hipMemsetAsync BEFORE this kernel (stream-ordered).
__global__ void k_init(const int* __restrict__ edges,
                       const float* __restrict__ w1, const float* __restrict__ b1,
                       const float* __restrict__ w2, const float* __restrict__ b2,
                       const float* __restrict__ attn_w, const float* __restrict__ attn_a,
                       const float* __restrict__ w_ih, const float* __restrict__ b_ih,
                       const float* __restrict__ b_hh, const float* __restrict__ b_out,
                       float* __restrict__ ws, float* __restrict__ out) {
  __shared__ float u_s[64], c1_s[64];
  int* iws = (int*)ws;
  int* cnt = iws + I_CNT;
  const int tid = threadIdx.x;
  const int g = blockIdx.x * 256 + tid;
  const int gsz = gridDim.x * 256;
  for (int i = g; i < NH * NE * NS; i += gsz)
    atomicAdd(&cnt[(i >> 14) * NV + edges[i]], 1);
  const float bo = b_out[0];
  for (int i = g; i < NB * NV; i += gsz) out[i] = bo;
  if (blockIdx.x == 0) {
    if (tid < 64) {
      float v1 = 0.f, v2 = 0.f, u = 0.f, c1 = 0.f;
      for (int d = 0; d < 64; ++d) {
        const float aw = attn_w[tid * 64 + d];
        v1 += aw * attn_a[d];
        v2 += aw * attn_a[64 + d];
        const float w2v = w2[d * 64 + tid];
        u  += w1[d] * w2v;
        c1 += b1[d] * w2v;
      }
      ws[S_U + tid] = u;  ws[S_C1 + tid] = c1;
      ws[S_V1 + tid] = v1; ws[S_V2 + tid] = v2;
      u_s[tid] = u; c1_s[tid] = c1;
    }
    __syncthreads();
    if (tid == 0) {
      float al = 0.f, be = 0.f, ga = 0.f, de = 0.f, ep = 0.f;
      for (int d = 0; d < 64; ++d) {
        const float v1 = ws[S_V1 + d], v2 = ws[S_V2 + d];
        al += u_s[d] * v1;  be += c1_s[d] * v1;
        ga += u_s[d] * v2;  de += c1_s[d] * v2;
        ep += b2[d] * (v1 + v2);
      }
      ws[S_SC + 0] = al; ws[S_SC + 1] = be; ws[S_SC + 2] = ga;
      ws[S_SC + 3] = de; ws[S_SC + 4] = ep;
    }
    {
      float gu = 0.f, gc = 0.f, g0 = 0.f;
      for (int d = 0; d < 64; ++d) {
        const float w = w_ih[tid * 64 + d];
        gu += w * u_s[d]; gc += w * c1_s[d]; g0 += w * b2[d];
      }
      ws[S_GU + tid] = gu; ws[S_GC + tid] = gc;
      ws[S_G0 + tid] = g0 + b_ih[tid] + b_hh[tid];
    }
  }
}

// ---------------- K2: offset scan + invdeg/mask (3 blocks x 256) ----------------
__global__ void k_scan(const int* __restrict__ counts, int* __restrict__ offs,
                       float* __restrict__ invdeg, float* __restrict__ mvec) {
  const int h = blockIdx.x;
  const int tid = threadIdx.x;
  const int base = h * NV;
  __shared__ int sd[256];
  int run = 0;
  for (int i = 0; i < 40; ++i) {
    const int v = tid * 40 + i;
    if (v < NV) run += counts[base + v];
  }
  sd[tid] = run;
  __syncthreads();
  int acc = run;
  for (int o2 = 1; o2 < 256; o2 <<= 1) {
    const int t = (tid >= o2) ? sd[tid - o2] : 0;
    __syncthreads();
    acc += t; sd[tid] = acc;
    __syncthreads();
  }
  int excl = acc - run;
  for (int i = 0; i < 40; ++i) {
    const int v = tid * 40 + i;
    if (v < NV) {
      const int c = counts[base + v];
      offs[base + v] = excl; excl += c;
      invdeg[base + v] = 1.0f / (float)((c > 0) ? c : 1);
      mvec[base + v] = (c > 0) ? 1.0f : 0.0f;
    }
  }
}

// ---------------- K3: CSR fill + transpose (independent work, fused) ----------------
__global__ void k_fill_trans(const int* __restrict__ edges, const float* __restrict__ s0,
                             const float* __restrict__ s1, float* __restrict__ ws,
                             int br0, int nbr, int do_fill) {
  __shared__ float tile[128][49];
  int* iws = (int*)ws;
  int* cur = iws + I_CUR;
  int* off = iws + I_OFF;
  int* sed = iws + I_SLOT;
  const int tid = threadIdx.x;
  const int g = blockIdx.x * 256 + tid;
  const int gsz = gridDim.x * 256;
  if (do_fill) {
    for (int i = g; i < NH * NE * NS; i += gsz) {
      const int h = i >> 14;
      const int e = (i >> 5) & (NE - 1);
      const int v = edges[i];
      const int pos = atomicAdd(&cur[h * NV + v], 1);
      sed[h * NE * NS + off[h * NV + v] + pos] = e;
    }
  }
  for (int task = blockIdx.x; task < nbr * NCHUNK; task += gridDim.x) {
    const int bi = task / NCHUNK;
    const int chunk = task - bi * NCHUNK;
    const float* seq = (br0 + bi) ? s1 : s0;
    float* o = ws + F_DYN + (size_t)bi * XT_SZ;
    const int v0 = chunk * 128;
    __syncthreads();
    for (int i = tid; i < 128 * NSEQ; i += 256) {
      const int n = i / 128, vl = i % 128;
      const int v = v0 + vl;
      tile[vl][n] = (v < NV) ? seq[n * NV + v] : 0.0f;
    }
    __syncthreads();
    for (int i = tid; i < 128 * NSEQ; i += 256) {
      const int vl = i / NSEQ, n = i % NSEQ;
      const int v = v0 + vl;
      if (v < NV) o[v * NSEQ + n] = tile[vl][n];
    }
  }
}

// ---------------- K4: edge-agg of raw x ----------------
__global__ void k_eagg1(const int* __restrict__ edges, float* __restrict__ ws, int nbr) {
  const int i = blockIdx.x * 256 + threadIdx.x;
  if (i >= nbr * T1) return;
  const int bi = i / T1;
  const int g = i - bi * T1;
  const float* x = ws + F_DYN + (size_t)bi * XT_SZ;
  float* a = ws + F_DYN + (size_t)nbr * XT_SZ + (size_t)bi * AGG_SZ;
  const int n0 = (g % 12) * 4;
  const int e = (g / 12) % NE;
  const int h = g / (12 * NE);
  const int* ep = edges + (h * NE + e) * NS;
  float4 acc = make_float4(0.f, 0.f, 0.f, 0.f);
  for (int s = 0; s < NS; ++s) {
    const float4 t = *(const float4*)&x[ep[s] * NSEQ + n0];
    acc.x += t.x; acc.y += t.y; acc.z += t.z; acc.w += t.w;
  }
  acc.x *= (1.0f / NS); acc.y *= (1.0f / NS); acc.z *= (1.0f / NS); acc.w *= (1.0f / NS);
  *(float4*)&a[(h * NE + e) * NSEQ + n0] = acc;
}

// ---------------- K5: vertex-agg 1 (normalized y) ----------------
__global__ void k_vg1(float* __restrict__ ws, int nbr) {
  const int i = blockIdx.x * 256 + threadIdx.x;
  if (i >= nbr * T2) return;
  int* iws = (int*)ws;
  const int* cnt = iws + I_CNT;
  const int* off = iws + I_OFF;
  const int* sed = iws + I_SLOT;
  const int bi = i / T2;
  const int g = i - bi * T2;
  const float* a = ws + F_DYN + (size_t)nbr * XT_SZ + (size_t)bi * AGG_SZ;
  float* y = ws + F_DYN + (size_t)nbr * (XT_SZ + AGG_SZ) + (size_t)bi * Y_SZ;
  const int n0 = (g % 12) * 4;
  const int v = (g / 12) % NV;
  const int h = g / (12 * NV);
  const int beg = off[h * NV + v];
  const int cv = cnt[h * NV + v];
  const int* se = sed + h * NE * NS;
  float4 acc = make_float4(0.f, 0.f, 0.f, 0.f);
  for (int k = 0; k < cv; ++k) {
    const int e = se[beg + k];
    const float4 t = *(const float4*)&a[(h * NE + e) * NSEQ + n0];
    acc.x += t.x; acc.y += t.y; acc.z += t.z; acc.w += t.w;
  }
  const float iv = ws[F_INV + h * NV + v];
  acc.x *= iv; acc.y *= iv; acc.z *= iv; acc.w *= iv;
  *(float4*)&y[(h * NV + v) * NSEQ + n0] = acc;
}

// ---------------- K6: edge-agg of y ----------------
__global__ void k_eagg2(const int* __restrict__ edges, float* __restrict__ ws, int nbr) {
  const int i = blockIdx.x * 256 + threadIdx.x;
  if (i >= nbr * T1) return;
  const int bi = i / T1;
  const int g = i - bi * T1;
  const float* y = ws + F_DYN + (size_t)nbr * (XT_SZ + AGG_SZ) + (size_t)bi * Y_SZ;
  float* a = ws + F_DYN + (size_t)nbr * XT_SZ + (size_t)bi * AGG_SZ;
  const int n0 = (g % 12) * 4;
  const int e = (g / 12) % NE;
  const int h = g / (12 * NE);
  const int* ep = edges + (h * NE + e) * NS;
  float4 acc = make_float4(0.f, 0.f, 0.f, 0.f);
  for (int s = 0; s < NS; ++s) {
    const float4 t = *(const float4*)&y[(h * NV + ep[s]) * NSEQ + n0];
    acc.x += t.x; acc.y += t.y; acc.z += t.z; acc.w += t.w;
  }
  acc.x *= (1.0f / NS); acc.y *= (1.0f / NS); acc.z *= (1.0f / NS); acc.w *= (1.0f / NS);
  *(float4*)&a[(h * NE + e) * NSEQ + n0] = acc;
}

// ---------------- K7: fused vertex-agg 2 + attention -> p,q ----------------
__global__ void k_vg2attn(float* __restrict__ ws, int nbr, int br0) {
  const int i = blockIdx.x * 256 + threadIdx.x;
  if (i >= nbr * T3) return;
  int* iws = (int*)ws;
  const int* cnt = iws + I_CNT;
  const int* off = iws + I_OFF;
  const int* sed = iws + I_SLOT;
  const int bi = i / T3;
  const int g = i - bi * T3;
  const float* a = ws + F_DYN + (size_t)nbr * XT_SZ + (size_t)bi * AGG_SZ;
  float* pbuf = ws + F_PQ + (size_t)(br0 + bi) * 2 * NV * NSEQ;
  float* qbuf = pbuf + NV * NSEQ;
  const int n0 = (g % 12) * 4;
  const int v = g / 12;
  const float al = ws[S_SC + 0], be = ws[S_SC + 1], ga = ws[S_SC + 2],
              de = ws[S_SC + 3], ep5 = ws[S_SC + 4];
  union { float4 v4; float f[4]; } zh[3], pv, qv;
  float mh[3];
  #pragma unroll
  for (int h = 0; h < NH; ++h) {
    const int beg = off[h * NV + v];
    const int cv = cnt[h * NV + v];
    const int* se = sed + h * NE * NS;
    float4 acc = make_float4(0.f, 0.f, 0.f, 0.f);
    for (int k = 0; k < cv; ++k) {
      const int e = se[beg + k];
      const float4 t = *(const float4*)&a[(h * NE + e) * NSEQ + n0];
      acc.x += t.x; acc.y += t.y; acc.z += t.z; acc.w += t.w;
    }
    const float iv = ws[F_INV + h * NV + v];
    acc.x *= iv; acc.y *= iv; acc.z *= iv; acc.w *= iv;
    zh[h].v4 = acc;
    mh[h] = ws[F_M + h * NV + v];
  }
  const float mb = (mh[0] + mh[1] + mh[2]) * (1.f / 3.f);
  #pragma unroll
  for (int j = 0; j < 4; ++j) {
    const float z0 = zh[0].f[j], z1 = zh[1].f[j], z2 = zh[2].f[j];
    const float zb = (z0 + z1 + z2) * (1.f / 3.f);
    const float zt[3] = {z0, z1, z2};
    float sc[3];
    #pragma unroll
    for (int h = 0; h < NH; ++h) {
      const float s = al * zt[h] + be * mh[h] + ga * zb + de * mb + ep5;
      sc[h] = (s > 0.f) ? s : 0.2f * s;
    }
    const float mx = fmaxf(sc[0], fmaxf(sc[1], sc[2]));
    const float e0 = __expf(sc[0] - mx), e1 = __expf(sc[1] - mx), e2 = __expf(sc[2] - mx);
    const float inv = 1.0f / (e0 + e1 + e2);
    pv.f[j] = (e0 * z0 + e1 * z1 + e2 * z2) * inv;
    qv.f[j] = (e0 * mh[0] + e1 * mh[1] + e2 * mh[2]) * inv;
  }
  *(float4*)&pbuf[v * NSEQ + n0] = pv.v4;
  *(float4*)&qbuf[v * NSEQ + n0] = qv.v4;
}

// ---------------- K8: barrier-free MFMA LSTM ----------------
// One WAVE owns 16 sequences x all 64 dims -> h never crosses waves; the D->A
// transpose round-trips a private LDS region with intra-wave lgkmcnt only.
// NO __syncthreads in the 12-step loop. w_hh stays LDS-resident (XOR-swizzled
// rows: plain 128B rows would 16-way-conflict every B read); B streams from LDS
// each step (register B would need 128 VGPRs). asm-laundered offset stops LICM
// from hoisting 32 loop-invariant b128 loads (round-7 spill lesson: never force
// launch_bounds below natural VGPR need either).
#define RSH 136  // h row stride (ushorts): 64 hi + 64 lo + 8 pad; 272 B, 16B-aligned
__launch_bounds__(256, 2)
__global__ void k_lstm3(const float* __restrict__ w_hh, const float* __restrict__ ws,
                        const float* __restrict__ pbase, const float* __restrict__ w_out,
                        float* __restrict__ out) {
  __shared__ __align__(16) unsigned short wlds[256 * 64];     // 32768 B (swizzled)
  __shared__ __align__(16) unsigned short hl[4 * 16 * RSH];   // 17408 B (per-wave h)
  __shared__ unsigned int pq_sh[4][NTT][16];                  // 3072 B (bf16 p|q)
  const int tid = threadIdx.x;
  const int w = tid >> 6, lane = tid & 63, q = lane >> 4, l15 = lane & 15;
  const int b = blockIdx.y, br = blockIdx.z;
  const int v0 = blockIdx.x * 64 + w * 16;  // this wave's 16 sequences

  // stage w_hh fp32 [256][64] -> wlds bf16, XOR-swizzled 8-ushort chunks
  for (int i = tid; i < 4096; i += 256) {
    const float4 w4 = ((const float4*)w_hh)[i];
    const int j = i >> 4, k = (i & 15) * 4;
    const int col = (((k >> 3) ^ (j & 7)) << 3) | (k & 7);
    uint2 pk;
    pk.x = (unsigned int)f2bf(w4.x) | ((unsigned int)f2bf(w4.y) << 16);
    pk.y = (unsigned int)f2bf(w4.z) | ((unsigned int)f2bf(w4.w) << 16);
    *(uint2*)&wlds[j * 64 + col] = pk;
  }
  // stage this wave's p,q (16 seqs x 12 t), packed bf16
  const float* pp = pbase + (size_t)br * 2 * NV * NSEQ;
  const float* qq = pp + NV * NSEQ;
  if (lane < 48) {
    const int s = lane / 3, f4 = lane % 3;
    const int v = v0 + s;
    float4 vp = make_float4(0.f, 0.f, 0.f, 0.f);
    float4 vq = vp;
    if (v < NV) {
      const int idx = v * NSEQ + b * NTT + f4 * 4;
      vp = *(const float4*)&pp[idx];
      vq = *(const float4*)&qq[idx];
    }
    pq_sh[w][f4 * 4 + 0][s] = (unsigned int)f2bf(vp.x) | ((unsigned int)f2bf(vq.x) << 16);
    pq_sh[w][f4 * 4 + 1][s] = (unsigned int)f2bf(vp.y) | ((unsigned int)f2bf(vq.y) << 16);
    pq_sh[w][f4 * 4 + 2][s] = (unsigned int)f2bf(vp.z) | ((unsigned int)f2bf(vq.z) << 16);
    pq_sh[w][f4 * 4 + 3][s] = (unsigned int)f2bf(vp.w) | ((unsigned int)f2bf(vq.w) << 16);
  }
  // per-lane weights: 4 dims (u*16+l15) x 4 gates
  float GU[4][4], GC[4][4], G0[4][4], WO[4];
  #pragma unroll
  for (int g = 0; g < 4; ++g)
    #pragma unroll
    for (int u = 0; u < 4; ++u) {
      const int j = g * 64 + u * 16 + l15;
      GU[g][u] = ws[S_GU + j];
      GC[g][u] = ws[S_GC + j];
      G0[g][u] = ws[S_G0 + j];
    }
  #pragma unroll
  for (int u = 0; u < 4; ++u) WO[u] = w_out[br * 64 + u * 16 + l15];
  __syncthreads();  // the ONLY block-wide barrier: wlds + pq ready

  unsigned short* hwv = hl + w * (16 * RSH);  // this wave's private h region
  f32x4 acc[4][4];  // [gate][dim-subtile]
  f32x4 cst[4];     // cell state [dim-subtile][r]
  float pout[4] = {0.f, 0.f, 0.f, 0.f};
  #pragma unroll
  for (int u = 0; u < 4; ++u) cst[u] = (f32x4){0.f, 0.f, 0.f, 0.f};

  int bofs = 0;
  #pragma unroll 1
  for (int t = 0; t < NTT; ++t) {
    asm volatile("" : "+v"(bofs));  // defeat LICM of the loop-invariant B loads
    // xg = p*GU + q*GC + G0 ; D-layout: row(seq)=q*4+r, col(dim)=u*16+l15
    float pv[4], qv[4];
    #pragma unroll
    for (int r = 0; r < 4; ++r) {
      const unsigned int u32v = pq_sh[w][t][q * 4 + r];
      pv[r] = __uint_as_float(u32v << 16);
      qv[r] = __uint_as_float(u32v & 0xffff0000u);
    }
    #pragma unroll
    for (int g = 0; g < 4; ++g)
      #pragma unroll
      for (int u = 0; u < 4; ++u)
        #pragma unroll
        for (int r = 0; r < 4; ++r)
          acc[g][u][r] = fmaf(pv[r], GU[g][u], fmaf(qv[r], GC[g][u], G0[g][u]));
    if (t > 0) {
      #pragma unroll
      for (int kh = 0; kh < 2; ++kh) {
        // A: h[m=l15][k=kh*32+q*8+j], hi and lo planes
        const bf16x8 Ahi = ldsA(&hwv[l15 * RSH + kh * 32 + q * 8]);
        const bf16x8 Alo = ldsA(&hwv[l15 * RSH + 64 + kh * 32 + q * 8]);
        #pragma unroll
        for (int u = 0; u < 4; ++u)
          #pragma unroll
          for (int g = 0; g < 4; ++g) {
            const int row = g * 64 + u * 16 + l15;
            const int col = ((kh * 4 + q) ^ (l15 & 7)) << 3;  // swizzled chunk
            const bf16x8 Bf = ldsA(&wlds[bofs + row * 64 + col]);
            acc[g][u] = __builtin_amdgcn_mfma_f32_16x16x32_bf16(Ahi, Bf, acc[g][u], 0, 0, 0);
            acc[g][u] = __builtin_amdgcn_mfma_f32_16x16x32_bf16(Alo, Bf, acc[g][u], 0, 0, 0);
          }
      }
    }
    const bool last = (t == NTT - 1);
    #pragma unroll
    for (int u = 0; u < 4; ++u)
      #pragma unroll
      for (int r = 0; r < 4; ++r) {
        const float ig = sigf(acc[0][u][r]);
        const float fg = sigf(acc[1][u][r]);
        const float gg = tanh_fast(acc[2][u][r]);
        const float og = sigf(acc[3][u][r]);
        const float cn = fmaf(fg, cst[u][r], ig * gg);
        cst[u][r] = cn;
        const float h = og * tanh_fast(cn);
        if (!last) {
          const unsigned short hi = f2bf(h);
          const unsigned short lo = f2bf(h - bf2f(hi));
          hwv[(q * 4 + r) * RSH + u * 16 + l15] = hi;
          hwv[(q * 4 + r) * RSH + 64 + u * 16 + l15] = lo;
        } else {
          pout[r] = fmaf(h, WO[u], pout[r]);
        }
      }
    // no barrier: next step's A-reads are intra-wave (compiler inserts lgkmcnt)
  }
  // reduce over the 16 lanes (dims) of each quad-row; one atomicAdd per seq
  #pragma unroll
  for (int r = 0; r < 4; ++r) {
    float v = pout[r];
    v += __shfl_xor(v, 1);
    v += __shfl_xor(v, 2);
    v += __shfl_xor(v, 4);
    v += __shfl_xor(v, 8);
    if (l15 == 0) {
      const int vv = v0 + q * 4 + r;
      if (vv < NV) atomicAdd(&out[b * NV + vv], v);
    }
  }
}

extern "C" void kernel_launch(void* const* d_in, const int* in_sizes, int n_in,
                              void* d_out, int out_size, void* d_ws, size_t ws_size,
                              hipStream_t stream) {
  const float* tend   = (const float*)d_in[0];
  const float* peri   = (const float*)d_in[1];
  const int*   edges  = (const int*)d_in[2];
  const float* w1     = (const float*)d_in[3];
  const float* b1     = (const float*)d_in[4];
  const float* w2     = (const float*)d_in[5];
  const float* b2     = (const float*)d_in[6];
  const float* attn_w = (const float*)d_in[7];
  const float* attn_a = (const float*)d_in[8];
  const float* w_ih   = (const float*)d_in[9];
  const float* w_hh   = (const float*)d_in[10];
  const float* b_ih   = (const float*)d_in[11];
  const float* b_hh   = (const float*)d_in[12];
  const float* w_out  = (const float*)d_in[13];
  const float* b_out  = (const float*)d_in[14];
  float* out = (float*)d_out;
  float* ws  = (float*)d_ws;
  int*   iws = (int*)d_ws;
  int* cnt = iws + I_CNT;
  int* off = iws + I_OFF;

  const size_t need2 = ((size_t)F_DYN + 2 * (XT_SZ + AGG_SZ + Y_SZ)) * 4;
  const bool batched = ws_size >= need2;

  hipMemsetAsync((char*)d_ws + (size_t)I_CNT * 4, 0, (size_t)2 * NH * NV * 4, stream);
  k_init<<<192, 256, 0, stream>>>(edges, w1, b1, w2, b2, attn_w, attn_a,
                                  w_ih, b_ih, b_hh, b_out, ws, out);
  k_scan<<<NH, 256, 0, stream>>>(cnt, off, ws + F_INV, ws + F_M);

  if (batched) {
    k_fill_trans<<<512, 256, 0, stream>>>(edges, tend, peri, ws, 0, 2, 1);
    k_eagg1<<<(2 * T1 + 255) / 256, 256, 0, stream>>>(edges, ws, 2);
    k_vg1<<<(2 * T2 + 255) / 256, 256, 0, stream>>>(ws, 2);
    k_eagg2<<<(2 * T1 + 255) / 256, 256, 0, stream>>>(edges, ws, 2);
    k_vg2attn<<<(2 * T3 + 255) / 256, 256, 0, stream>>>(ws, 2, 0);
  } else {
    for (int br = 0; br < 2; ++br) {
      k_fill_trans<<<512, 256, 0, stream>>>(edges, tend, peri, ws, br, 1, br == 0 ? 1 : 0);
      k_eagg1<<<(T1 + 255) / 256, 256, 0, stream>>>(edges, ws, 1);
      k_vg1<<<(T2 + 255) / 256, 256, 0, stream>>>(ws, 1);
      k_eagg2<<<(T1 + 255) / 256, 256, 0, stream>>>(edges, ws, 1);
      k_vg2attn<<<(T3 + 255) / 256, 256, 0, stream>>>(ws, 1, br);
    }
  }
  dim3 lgrid((NV + 63) / 64, NB, 2);
  k_lstm3<<<lgrid, 256, 0, stream>>>(w_hh, ws, ws + F_PQ, w_out, out);
}

// Round 10
// 298.410 us; speedup vs baseline: 3.9851x; 1.2632x over previous
//
#include <hip/hip_runtime.h>

#define NV 10000
#define NB 4
#define NTT 12
#define NSEQ 48
#define NH 3
#define NE 512
#define NS 32
#define ND 64

// ---- fixed workspace layout (element indices; float and int regions share the base) ----
#define S_U   0
#define S_C1  64
#define S_V1  128
#define S_V2  192
#define S_SC  256
#define S_GU  272
#define S_GC  528
#define S_G0  784
#define F_INV 1040
#define F_M   (F_INV + NH*NV)            // 31040
#define F_PQ  (F_M + NH*NV)              // 61040  (4 x NV*NSEQ: p0,q0,p1,q1)
#define F_HT  (F_PQ + 4*NV*NSEQ)         // 1981040 (kept for layout stability)
#define I_CNT (F_HT + 2*NB*NV)           // 2061040
#define I_CUR (I_CNT + NH*NV)
#define I_OFF (I_CUR + NH*NV)
#define I_SLOT (I_OFF + NH*NV)
#define F_DYN (I_SLOT + NH*NE*NS)        // 2200192
#define XT_SZ  (NV*NSEQ)                 // 480000
#define AGG_SZ (NH*NE*NSEQ)              // 73728
#define Y_SZ   (NH*NV*NSEQ)              // 1440000

#define T1 (NH*NE*12)                    // 18432 edge float4-groups
#define T2 (NH*NV*12)                    // 360000 vertex float4-groups
#define T3 (NV*12)                       // 120000 attn float4-groups
#define NCHUNK 79                        // ceil(NV/128)

typedef __attribute__((ext_vector_type(8))) __bf16 bf16x8;
typedef __attribute__((ext_vector_type(4))) float f32x4;

__device__ __forceinline__ float sigf(float x) {
  return __builtin_amdgcn_rcpf(1.0f + __expf(-x));
}
__device__ __forceinline__ float tanh_fast(float x) {
  return 1.0f - 2.0f * __builtin_amdgcn_rcpf(1.0f + __expf(2.0f * x));
}
__device__ __forceinline__ unsigned short f2bf(float x) {
  unsigned int u = __float_as_uint(x);
  u = (u + 0x7fffu + ((u >> 16) & 1u)) >> 16;
  return (unsigned short)u;
}
__device__ __forceinline__ float bf2f(unsigned short h) {
  return __uint_as_float(((unsigned int)h) << 16);
}
__device__ __forceinline__ bf16x8 ldsA(const unsigned short* p) {
  union { uint4 u; bf16x8 v; } x;
  x.u = *(const uint4*)p;
  return x.v;
}

// ---------------- K1: out init + weight precompute + degree count ----------------
// cnt/cur are zeroed by hipMemsetAsync BEFORE this kernel (stream-ordered).
__global__ void k_init(const int* __restrict__ edges,
                       const float* __restrict__ w1, const float* __restrict__ b1,
                       const float* __restrict__ w2, const float* __restrict__ b2,
                       const float* __restrict__ attn_w, const float* __restrict__ attn_a,
                       const float* __restrict__ w_ih, const float* __restrict__ b_ih,
                       const float* __restrict__ b_hh, const float* __restrict__ b_out,
                       float* __restrict__ ws, float* __restrict__ out) {
  __shared__ float u_s[64], c1_s[64];
  int* iws = (int*)ws;
  int* cnt = iws + I_CNT;
  const int tid = threadIdx.x;
  const int g = blockIdx.x * 256 + tid;
  const int gsz = gridDim.x * 256;
  for (int i = g; i < NH * NE * NS; i += gsz)
    atomicAdd(&cnt[(i >> 14) * NV + edges[i]], 1);
  const float bo = b_out[0];
  for (int i = g; i < NB * NV; i += gsz) out[i] = bo;
  if (blockIdx.x == 0) {
    if (tid < 64) {
      float v1 = 0.f, v2 = 0.f, u = 0.f, c1 = 0.f;
      for (int d = 0; d < 64; ++d) {
        const float aw = attn_w[tid * 64 + d];
        v1 += aw * attn_a[d];
        v2 += aw * attn_a[64 + d];
        const float w2v = w2[d * 64 + tid];
        u  += w1[d] * w2v;
        c1 += b1[d] * w2v;
      }
      ws[S_U + tid] = u;  ws[S_C1 + tid] = c1;
      ws[S_V1 + tid] = v1; ws[S_V2 + tid] = v2;
      u_s[tid] = u; c1_s[tid] = c1;
    }
    __syncthreads();
    if (tid == 0) {
      float al = 0.f, be = 0.f, ga = 0.f, de = 0.f, ep = 0.f;
      for (int d = 0; d < 64; ++d) {
        const float v1 = ws[S_V1 + d], v2 = ws[S_V2 + d];
        al += u_s[d] * v1;  be += c1_s[d] * v1;
        ga += u_s[d] * v2;  de += c1_s[d] * v2;
        ep += b2[d] * (v1 + v2);
      }
      ws[S_SC + 0] = al; ws[S_SC + 1] = be; ws[S_SC + 2] = ga;
      ws[S_SC + 3] = de; ws[S_SC + 4] = ep;
    }
    {
      float gu = 0.f, gc = 0.f, g0 = 0.f;
      for (int d = 0; d < 64; ++d) {
        const float w = w_ih[tid * 64 + d];
        gu += w * u_s[d]; gc += w * c1_s[d]; g0 += w * b2[d];
      }
      ws[S_GU + tid] = gu; ws[S_GC + tid] = gc;
      ws[S_G0 + tid] = g0 + b_ih[tid] + b_hh[tid];
    }
  }
}

// ---------------- K2: offset scan + invdeg/mask (3 blocks x 256) ----------------
__global__ void k_scan(const int* __restrict__ counts, int* __restrict__ offs,
                       float* __restrict__ invdeg, float* __restrict__ mvec) {
  const int h = blockIdx.x;
  const int tid = threadIdx.x;
  const int base = h * NV;
  __shared__ int sd[256];
  int run = 0;
  for (int i = 0; i < 40; ++i) {
    const int v = tid * 40 + i;
    if (v < NV) run += counts[base + v];
  }
  sd[tid] = run;
  __syncthreads();
  int acc = run;
  for (int o2 = 1; o2 < 256; o2 <<= 1) {
    const int t = (tid >= o2) ? sd[tid - o2] : 0;
    __syncthreads();
    acc += t; sd[tid] = acc;
    __syncthreads();
  }
  int excl = acc - run;
  for (int i = 0; i < 40; ++i) {
    const int v = tid * 40 + i;
    if (v < NV) {
      const int c = counts[base + v];
      offs[base + v] = excl; excl += c;
      invdeg[base + v] = 1.0f / (float)((c > 0) ? c : 1);
      mvec[base + v] = (c > 0) ? 1.0f : 0.0f;
    }
  }
}

// ---------------- K3: CSR fill + transpose (independent work, fused) ----------------
__global__ void k_fill_trans(const int* __restrict__ edges, const float* __restrict__ s0,
                             const float* __restrict__ s1, float* __restrict__ ws,
                             int br0, int nbr, int do_fill) {
  __shared__ float tile[128][49];
  int* iws = (int*)ws;
  int* cur = iws + I_CUR;
  int* off = iws + I_OFF;
  int* sed = iws + I_SLOT;
  const int tid = threadIdx.x;
  const int g = blockIdx.x * 256 + tid;
  const int gsz = gridDim.x * 256;
  if (do_fill) {
    for (int i = g; i < NH * NE * NS; i += gsz) {
      const int h = i >> 14;
      const int e = (i >> 5) & (NE - 1);
      const int v = edges[i];
      const int pos = atomicAdd(&cur[h * NV + v], 1);
      sed[h * NE * NS + off[h * NV + v] + pos] = e;
    }
  }
  for (int task = blockIdx.x; task < nbr * NCHUNK; task += gridDim.x) {
    const int bi = task / NCHUNK;
    const int chunk = task - bi * NCHUNK;
    const float* seq = (br0 + bi) ? s1 : s0;
    float* o = ws + F_DYN + (size_t)bi * XT_SZ;
    const int v0 = chunk * 128;
    __syncthreads();
    for (int i = tid; i < 128 * NSEQ; i += 256) {
      const int n = i / 128, vl = i % 128;
      const int v = v0 + vl;
      tile[vl][n] = (v < NV) ? seq[n * NV + v] : 0.0f;
    }
    __syncthreads();
    for (int i = tid; i < 128 * NSEQ; i += 256) {
      const int vl = i / NSEQ, n = i % NSEQ;
      const int v = v0 + vl;
      if (v < NV) o[v * NSEQ + n] = tile[vl][n];
    }
  }
}

// ---------------- K4: edge-agg of raw x ----------------
__global__ void k_eagg1(const int* __restrict__ edges, float* __restrict__ ws, int nbr) {
  const int i = blockIdx.x * 256 + threadIdx.x;
  if (i >= nbr * T1) return;
  const int bi = i / T1;
  const int g = i - bi * T1;
  const float* x = ws + F_DYN + (size_t)bi * XT_SZ;
  float* a = ws + F_DYN + (size_t)nbr * XT_SZ + (size_t)bi * AGG_SZ;
  const int n0 = (g % 12) * 4;
  const int e = (g / 12) % NE;
  const int h = g / (12 * NE);
  const int* ep = edges + (h * NE + e) * NS;
  float4 acc = make_float4(0.f, 0.f, 0.f, 0.f);
  for (int s = 0; s < NS; ++s) {
    const float4 t = *(const float4*)&x[ep[s] * NSEQ + n0];
    acc.x += t.x; acc.y += t.y; acc.z += t.z; acc.w += t.w;
  }
  acc.x *= (1.0f / NS); acc.y *= (1.0f / NS); acc.z *= (1.0f / NS); acc.w *= (1.0f / NS);
  *(float4*)&a[(h * NE + e) * NSEQ + n0] = acc;
}

// ---------------- K5: vertex-agg 1, both branches per thread (CSR loads amortized) ----
__global__ void k_vg1(float* __restrict__ ws, int nbr) {
  const int g = blockIdx.x * 256 + threadIdx.x;
  if (g >= T2) return;
  int* iws = (int*)ws;
  const int* cnt = iws + I_CNT;
  const int* off = iws + I_OFF;
  const int* sed = iws + I_SLOT;
  const int n0 = (g % 12) * 4;
  const int v = (g / 12) % NV;
  const int h = g / (12 * NV);
  const int beg = off[h * NV + v];
  const int cv = cnt[h * NV + v];
  const int* se = sed + h * NE * NS;
  const float* a0 = ws + F_DYN + (size_t)nbr * XT_SZ;
  float* y0 = ws + F_DYN + (size_t)nbr * (XT_SZ + AGG_SZ);
  const int eo = (h * NE) * NSEQ + n0;
  float4 acc0 = make_float4(0.f, 0.f, 0.f, 0.f);
  float4 acc1 = acc0;
  for (int k = 0; k < cv; ++k) {
    const int e = se[beg + k];
    const float4 t0 = *(const float4*)&a0[eo + e * NSEQ];
    acc0.x += t0.x; acc0.y += t0.y; acc0.z += t0.z; acc0.w += t0.w;
    if (nbr == 2) {
      const float4 t1 = *(const float4*)&a0[AGG_SZ + eo + e * NSEQ];
      acc1.x += t1.x; acc1.y += t1.y; acc1.z += t1.z; acc1.w += t1.w;
    }
  }
  const float iv = ws[F_INV + h * NV + v];
  const int vo = (h * NV + v) * NSEQ + n0;
  acc0.x *= iv; acc0.y *= iv; acc0.z *= iv; acc0.w *= iv;
  *(float4*)&y0[vo] = acc0;
  if (nbr == 2) {
    acc1.x *= iv; acc1.y *= iv; acc1.z *= iv; acc1.w *= iv;
    *(float4*)&y0[Y_SZ + vo] = acc1;
  }
}

// ---------------- K6: edge-agg of y ----------------
__global__ void k_eagg2(const int* __restrict__ edges, float* __restrict__ ws, int nbr) {
  const int i = blockIdx.x * 256 + threadIdx.x;
  if (i >= nbr * T1) return;
  const int bi = i / T1;
  const int g = i - bi * T1;
  const float* y = ws + F_DYN + (size_t)nbr * (XT_SZ + AGG_SZ) + (size_t)bi * Y_SZ;
  float* a = ws + F_DYN + (size_t)nbr * XT_SZ + (size_t)bi * AGG_SZ;
  const int n0 = (g % 12) * 4;
  const int e = (g / 12) % NE;
  const int h = g / (12 * NE);
  const int* ep = edges + (h * NE + e) * NS;
  float4 acc = make_float4(0.f, 0.f, 0.f, 0.f);
  for (int s = 0; s < NS; ++s) {
    const float4 t = *(const float4*)&y[(h * NV + ep[s]) * NSEQ + n0];
    acc.x += t.x; acc.y += t.y; acc.z += t.z; acc.w += t.w;
  }
  acc.x *= (1.0f / NS); acc.y *= (1.0f / NS); acc.z *= (1.0f / NS); acc.w *= (1.0f / NS);
  *(float4*)&a[(h * NE + e) * NSEQ + n0] = acc;
}

// ---------------- K7: fused vertex-agg 2 + attention, both branches per thread -------
__global__ void k_vg2attn(float* __restrict__ ws, int nbr, int br0) {
  const int g = blockIdx.x * 256 + threadIdx.x;
  if (g >= T3) return;
  int* iws = (int*)ws;
  const int* cnt = iws + I_CNT;
  const int* off = iws + I_OFF;
  const int* sed = iws + I_SLOT;
  const int n0 = (g % 12) * 4;
  const int v = g / 12;
  const float al = ws[S_SC + 0], be = ws[S_SC + 1], ga = ws[S_SC + 2],
              de = ws[S_SC + 3], ep5 = ws[S_SC + 4];
  const float* a0 = ws + F_DYN + (size_t)nbr * XT_SZ;
  union { float4 v4; float f[4]; } zh[2][3], pv, qv;
  float mh[3];
  #pragma unroll
  for (int h = 0; h < NH; ++h) {
    const int beg = off[h * NV + v];
    const int cv = cnt[h * NV + v];
    const int* se = sed + h * NE * NS;
    const int eo = (h * NE) * NSEQ + n0;
    float4 acc0 = make_float4(0.f, 0.f, 0.f, 0.f);
    float4 acc1 = acc0;
    for (int k = 0; k < cv; ++k) {
      const int e = se[beg + k];
      const float4 t0 = *(const float4*)&a0[eo + e * NSEQ];
      acc0.x += t0.x; acc0.y += t0.y; acc0.z += t0.z; acc0.w += t0.w;
      if (nbr == 2) {
        const float4 t1 = *(const float4*)&a0[AGG_SZ + eo + e * NSEQ];
        acc1.x += t1.x; acc1.y += t1.y; acc1.z += t1.z; acc1.w += t1.w;
      }
    }
    const float iv = ws[F_INV + h * NV + v];
    acc0.x *= iv; acc0.y *= iv; acc0.z *= iv; acc0.w *= iv;
    zh[0][h].v4 = acc0;
    if (nbr == 2) {
      acc1.x *= iv; acc1.y *= iv; acc1.z *= iv; acc1.w *= iv;
      zh[1][h].v4 = acc1;
    }
    mh[h] = ws[F_M + h * NV + v];
  }
  const float mb = (mh[0] + mh[1] + mh[2]) * (1.f / 3.f);
  for (int bi = 0; bi < nbr; ++bi) {
    float* pbuf = ws + F_PQ + (size_t)(br0 + bi) * 2 * NV * NSEQ;
    float* qbuf = pbuf + NV * NSEQ;
    #pragma unroll
    for (int j = 0; j < 4; ++j) {
      const float z0 = zh[bi][0].f[j], z1 = zh[bi][1].f[j], z2 = zh[bi][2].f[j];
      const float zb = (z0 + z1 + z2) * (1.f / 3.f);
      const float zt[3] = {z0, z1, z2};
      float sc[3];
      #pragma unroll
      for (int h = 0; h < NH; ++h) {
        const float s = al * zt[h] + be * mh[h] + ga * zb + de * mb + ep5;
        sc[h] = (s > 0.f) ? s : 0.2f * s;
      }
      const float mx = fmaxf(sc[0], fmaxf(sc[1], sc[2]));
      const float e0 = __expf(sc[0] - mx), e1 = __expf(sc[1] - mx), e2 = __expf(sc[2] - mx);
      const float inv = 1.0f / (e0 + e1 + e2);
      pv.f[j] = (e0 * z0 + e1 * z1 + e2 * z2) * inv;
      qv.f[j] = (e0 * mh[0] + e1 * mh[1] + e2 * mh[2]) * inv;
    }
    *(float4*)&pbuf[v * NSEQ + n0] = pv.v4;
    *(float4*)&qbuf[v * NSEQ + n0] = qv.v4;
  }
}

// ---------------- K8: MFMA LSTM (round-5 proven structure, 143 us) ----------------
// Block: 64 vertices (seqs), batch b = blockIdx.y, branch = blockIdx.z.
// gates = xg + h @ w_hh^T via mfma_f32_16x16x32_bf16; h carried as split bf16 hi+lo.
// w_hh staged once (no pad) into LDS; region then reused as h double-buffer.
// B-fragments live in REGISTERS across all steps (streaming them from LDS each
// step regressed: round 9). VGPR need ~116 — never bound below 128 (round 7).
#define RS  136  // h row stride (ushorts): 64 hi + 64 lo + 8 pad, 272 B (16B-aligned)
__launch_bounds__(256, 2)
__global__ void k_lstm2(const float* __restrict__ w_hh, const float* __restrict__ ws,
                        const float* __restrict__ pbase, const float* __restrict__ w_out,
                        float* __restrict__ out) {
  __shared__ __align__(16) unsigned short smem[2 * 64 * RS];  // 34816 B
  __shared__ float ps_sh[NTT][64], qs_sh[NTT][64];            // 6144 B
  const int tid = threadIdx.x;
  const int w = tid >> 6, lane = tid & 63, q = lane >> 4, l15 = lane & 15;
  const int b = blockIdx.y, br = blockIdx.z;
  const int v0 = blockIdx.x * 64;
  const int d = w * 16 + l15;  // this lane's gate-dim within [0,64)

  // coalesced stage: w_hh fp32 [256][64] -> smem bf16 [j][64] (no pad; one-time)
  for (int i = tid; i < 4096; i += 256) {
    const float4 w4 = ((const float4*)w_hh)[i];
    const int j = i >> 4, k = (i & 15) * 4;
    uint2 pk;
    pk.x = (unsigned int)f2bf(w4.x) | ((unsigned int)f2bf(w4.y) << 16);
    pk.y = (unsigned int)f2bf(w4.z) | ((unsigned int)f2bf(w4.w) << 16);
    *(uint2*)&smem[j * 64 + k] = pk;
  }
  // stage p,q for all 12 steps (float4 over t)
  const float* pp = pbase + (size_t)br * 2 * NV * NSEQ;
  const float* qq = pp + NV * NSEQ;
  for (int i = tid; i < 384; i += 256) {
    const int arr = (i >= 192) ? 1 : 0;
    const int ii = i - arr * 192;
    const int s = ii / 3, f4 = ii % 3;
    const int v = v0 + s;
    const float* src = arr ? qq : pp;
    float4 val = make_float4(0.f, 0.f, 0.f, 0.f);
    if (v < NV) val = *(const float4*)&src[v * NSEQ + b * NTT + f4 * 4];
    float (*dst)[64] = arr ? qs_sh : ps_sh;
    dst[f4 * 4 + 0][s] = val.x; dst[f4 * 4 + 1][s] = val.y;
    dst[f4 * 4 + 2][s] = val.z; dst[f4 * 4 + 3][s] = val.w;
  }
  __syncthreads();

  // B fragments from LDS: B[k][n=gate g*64+d], k = kh*32 + q*8 + j (one-time, conflicts ok)
  bf16x8 Bf[4][2];
  #pragma unroll
  for (int g = 0; g < 4; ++g)
    #pragma unroll
    for (int kh = 0; kh < 2; ++kh)
      Bf[g][kh] = ldsA(&smem[(g * 64 + d) * 64 + kh * 32 + q * 8]);

  float GUr[4], GCr[4], G0r[4];
  #pragma unroll
  for (int g = 0; g < 4; ++g) {
    GUr[g] = ws[S_GU + g * 64 + d];
    GCr[g] = ws[S_GC + g * 64 + d];
    G0r[g] = ws[S_G0 + g * 64 + d];
  }
  const float WO = w_out[br * 64 + d];
  __syncthreads();  // all waves done reading w-stage; reuse smem as h dbuf

  f32x4 acc[4][4];  // [mi seq-tile][g gate-type]
  f32x4 cst[4];
  float pr[4][4];   // last-step output partials
  #pragma unroll
  for (int mi = 0; mi < 4; ++mi) cst[mi] = (f32x4){0.f, 0.f, 0.f, 0.f};

  #pragma unroll 1
  for (int t = 0; t < NTT; ++t) {
    // input contribution: xg = p*GU + q*GC + G0 (D layout: row s=mi*16+q*4+r, col d)
    #pragma unroll
    for (int mi = 0; mi < 4; ++mi)
      #pragma unroll
      for (int r = 0; r < 4; ++r) {
        const int s = mi * 16 + q * 4 + r;
        const float pv = ps_sh[t][s], qv = qs_sh[t][s];
        #pragma unroll
        for (int g = 0; g < 4; ++g)
          acc[mi][g][r] = fmaf(pv, GUr[g], fmaf(qv, GCr[g], G0r[g]));
      }
    if (t > 0) {
      const unsigned short* hr = smem + ((t - 1) & 1) * (64 * RS);
      #pragma unroll
      for (int kh = 0; kh < 2; ++kh)
        #pragma unroll
        for (int mi = 0; mi < 4; ++mi) {
          const int row = mi * 16 + l15;  // A layout: m = lane&15
          const int col = kh * 32 + q * 8;
          const bf16x8 Ahi = ldsA(&hr[row * RS + col]);
          const bf16x8 Alo = ldsA(&hr[row * RS + 64 + col]);
          #pragma unroll
          for (int g = 0; g < 4; ++g) {
            acc[mi][g] = __builtin_amdgcn_mfma_f32_16x16x32_bf16(Ahi, Bf[g][kh], acc[mi][g], 0, 0, 0);
            acc[mi][g] = __builtin_amdgcn_mfma_f32_16x16x32_bf16(Alo, Bf[g][kh], acc[mi][g], 0, 0, 0);
          }
        }
    }
    unsigned short* hw = smem + (t & 1) * (64 * RS);
    const bool last = (t == NTT - 1);
    #pragma unroll
    for (int mi = 0; mi < 4; ++mi)
      #pragma unroll
      for (int r = 0; r < 4; ++r) {
        const float ig = sigf(acc[mi][0][r]);
        const float fg = sigf(acc[mi][1][r]);
        const float gg = tanh_fast(acc[mi][2][r]);
        const float og = sigf(acc[mi][3][r]);
        const float cn = fmaf(fg, cst[mi][r], ig * gg);
        cst[mi][r] = cn;
        const float h = og * tanh_fast(cn);
        const int s = mi * 16 + q * 4 + r;
        if (!last) {
          const unsigned short hi = f2bf(h);
          const unsigned short lo = f2bf(h - bf2f(hi));
          hw[s * RS + d] = hi;
          hw[s * RS + 64 + d] = lo;
        } else {
          pr[mi][r] = h * WO;
        }
      }
    __syncthreads();
  }
  // cross-lane (16 dims of this wave) then cross-wave reduce via the dead h buffer
  float* fbuf = (float*)smem;
  #pragma unroll
  for (int mi = 0; mi < 4; ++mi)
    #pragma unroll
    for (int r = 0; r < 4; ++r) {
      float v = pr[mi][r];
      v += __shfl_xor(v, 1);
      v += __shfl_xor(v, 2);
      v += __shfl_xor(v, 4);
      v += __shfl_xor(v, 8);
      if (l15 == 0) fbuf[w * 64 + mi * 16 + q * 4 + r] = v;
    }
  __syncthreads();
  if (tid < 64) {
    const int v = v0 + tid;
    if (v < NV)
      atomicAdd(&out[b * NV + v],
                fbuf[tid] + fbuf[64 + tid] + fbuf[128 + tid] + fbuf[192 + tid]);
  }
}

extern "C" void kernel_launch(void* const* d_in, const int* in_sizes, int n_in,
                              void* d_out, int out_size, void* d_ws, size_t ws_size,
                              hipStream_t stream) {
  const float* tend   = (const float*)d_in[0];
  const float* peri   = (const float*)d_in[1];
  const int*   edges  = (const int*)d_in[2];
  const float* w1     = (const float*)d_in[3];
  const float* b1     = (const float*)d_in[4];
  const float* w2     = (const float*)d_in[5];
  const float* b2     = (const float*)d_in[6];
  const float* attn_w = (const float*)d_in[7];
  const float* attn_a = (const float*)d_in[8];
  const float* w_ih   = (const float*)d_in[9];
  const float* w_hh   = (const float*)d_in[10];
  const float* b_ih   = (const float*)d_in[11];
  const float* b_hh   = (const float*)d_in[12];
  const float* w_out  = (const float*)d_in[13];
  const float* b_out  = (const float*)d_in[14];
  float* out = (float*)d_out;
  float* ws  = (float*)d_ws;
  int*   iws = (int*)d_ws;
  int* cnt = iws + I_CNT;
  int* off = iws + I_OFF;

  const size_t need2 = ((size_t)F_DYN + 2 * (XT_SZ + AGG_SZ + Y_SZ)) * 4;
  const bool batched = ws_size >= need2;

  hipMemsetAsync((char*)d_ws + (size_t)I_CNT * 4, 0, (size_t)2 * NH * NV * 4, stream);
  k_init<<<192, 256, 0, stream>>>(edges, w1, b1, w2, b2, attn_w, attn_a,
                                  w_ih, b_ih, b_hh, b_out, ws, out);
  k_scan<<<NH, 256, 0, stream>>>(cnt, off, ws + F_INV, ws + F_M);

  if (batched) {
    k_fill_trans<<<512, 256, 0, stream>>>(edges, tend, peri, ws, 0, 2, 1);
    k_eagg1<<<(2 * T1 + 255) / 256, 256, 0, stream>>>(edges, ws, 2);
    k_vg1<<<(T2 + 255) / 256, 256, 0, stream>>>(ws, 2);
    k_eagg2<<<(2 * T1 + 255) / 256, 256, 0, stream>>>(edges, ws, 2);
    k_vg2attn<<<(T3 + 255) / 256, 256, 0, stream>>>(ws, 2, 0);
  } else {
    for (int br = 0; br < 2; ++br) {
      k_fill_trans<<<512, 256, 0, stream>>>(edges, tend, peri, ws, br, 1, br == 0 ? 1 : 0);
      k_eagg1<<<(T1 + 255) / 256, 256, 0, stream>>>(edges, ws, 1);
      k_vg1<<<(T2 + 255) / 256, 256, 0, stream>>>(ws, 1);
      k_eagg2<<<(T1 + 255) / 256, 256, 0, stream>>>(edges, ws, 1);
      k_vg2attn<<<(T3 + 255) / 256, 256, 0, stream>>>(ws, 1, br);
    }
  }
  dim3 lgrid((NV + 63) / 64, NB, 2);
  k_lstm2<<<lgrid, 256, 0, stream>>>(w_hh, ws, ws + F_PQ, w_out, out);
}